// Round 6
// baseline (171.826 us; speedup 1.0000x reference)
//
#include <hip/hip_runtime.h>

// S4D real: y[l,c] = sum_s w[c,s] * h_s[l],  h_s[l] = x[l,c] + r[c,s]*h_s[l-1]
//
// R11: TWO dispatches, BOTH high-occupancy (R10's regression was its
// 128-block serial strip K1: 0.5 blocks/CU, ~12us of exposed HBM latency).
//   K1 k_local (R7's proven body, T=64): 512 blocks, 4 waves x 16 states,
//     zero-carry chunk scan -> chunk-end states E[64][SC] (8 MB).
//   K2 k_scan3: carry-in rebuilt IN REGISTERS by Horner over previous
//     chunk-ends:  G = sum_{j<k} rT^{k-1-j} E[j]   (rT = r^64, 6 squarings;
//     A_j = E_j + rT*A_{j-1} => carry-in(k) = A_{k-1}, forward Horner).
//     E is L2-resident (8 MB); redundant volume sum_k k*SC*4B ~ 264 MB of
//     L2 reads ~ 8us; avg 32 Horner iters ~ 1024 cyc/wave extra VALU.
//     Then R7's proven seeded chunk scan + LDS cross-wave y reduce.
//   Reverse block->chunk mapping: heaviest (large-k) blocks start first.
// No atomics, no global barrier (R9: 1024 pollers on one cacheline = 510us).
// Window model: dur ~= fill(41-46us) + kernels + ~6us/boundary.

namespace {

constexpr int L_ = 4096;
constexpr int CH_ = 512;
constexpr int S_ = 64;
constexpr float DT = 1.0f / 4096.0f;
constexpr int SC = S_ * CH_;   // 32768 (s,c) pairs
constexpr int SG = 16;         // states per thread (S_ / 4 waves)
constexpr int T_ = 64;         // chunk length
constexpr int NC_ = L_ / T_;   // 64 chunks

// Compute r (and optionally w) for states [s0, s0+16) of channel c.
__device__ __forceinline__ void params16(const float* __restrict__ la,
                                         const float* __restrict__ Bg,
                                         const float* __restrict__ Cg,
                                         int c, int s0, float* r, float* w) {
  const float4* lap = reinterpret_cast<const float4*>(la + c * S_ + s0);
  if (w == nullptr) {
#pragma unroll
    for (int q = 0; q < 4; ++q) {
      const float4 v = lap[q];
      const float a[4] = {v.x, v.y, v.z, v.w};
#pragma unroll
      for (int t = 0; t < 4; ++t) {
        const float A = -expf(a[t]);
        r[q * 4 + t] = expf(A * DT);
      }
    }
  } else {
    const float4* bp = reinterpret_cast<const float4*>(Bg + c * S_ + s0);
    const float4* cp = reinterpret_cast<const float4*>(Cg + c * S_ + s0);
#pragma unroll
    for (int q = 0; q < 4; ++q) {
      const float4 v = lap[q], bb = bp[q], cc = cp[q];
      const float a[4] = {v.x, v.y, v.z, v.w};
      const float bv[4] = {bb.x, bb.y, bb.z, bb.w};
      const float cv[4] = {cc.x, cc.y, cc.z, cc.w};
#pragma unroll
      for (int t = 0; t < 4; ++t) {
        const float A = -expf(a[t]);
        const float rr = expf(A * DT);
        r[q * 4 + t] = rr;
        w[q * 4 + t] = cv[t] * ((rr - 1.0f) * bv[t] / A);
      }
    }
  }
}

// ---------------- K1: local chunk-end states (zero carry-in) ----------------
// grid = NC_*8 = 512 blocks, 256 thr. wave g: states [16g,16g+16), lane: c.
__global__ __launch_bounds__(256, 4)
void k_local(const float* __restrict__ x, const float* __restrict__ la,
             float* __restrict__ E) {
  const int lane = threadIdx.x & 63;
  const int g = threadIdx.x >> 6;
  const int k = blockIdx.x >> 3;
  const int c = ((blockIdx.x & 7) << 6) + lane;
  const int s0 = g * SG;

  float r[SG], h[SG];
  params16(la, nullptr, nullptr, c, s0, r, nullptr);
#pragma unroll
  for (int i = 0; i < SG; ++i) h[i] = 0.0f;

  const float* xp = x + (size_t)k * T_ * CH_ + c;
#pragma unroll 8
  for (int l = 0; l < T_; ++l) {
    const float xv = xp[l * CH_];
#pragma unroll
    for (int i = 0; i < SG; ++i) h[i] = fmaf(r[i], h[i], xv);
  }

  float* ew = E + (size_t)k * SC + s0 * CH_ + c;
#pragma unroll
  for (int i = 0; i < SG; ++i) ew[i * CH_] = h[i];
}

// ---------------- K2: Horner carry-in + seeded re-scan + output -------------
// grid = NC_*8 = 512 blocks. Reverse chunk mapping: heavy blocks first.
__global__ __launch_bounds__(256, 4)
void k_scan3(const float* __restrict__ x, const float* __restrict__ la,
             const float* __restrict__ Bg, const float* __restrict__ Cg,
             const float* __restrict__ E, float* __restrict__ y) {
  __shared__ float lds[4][8][64];  // [s-group][l-row][lane]

  const int lane = threadIdx.x & 63;
  const int g = threadIdx.x >> 6;
  const int k = (NC_ - 1) - (int)(blockIdx.x >> 3);  // heavy first
  const int cb = (blockIdx.x & 7) << 6;
  const int c = cb + lane;
  const int s0 = g * SG;

  float r[SG], w[SG], h[SG];
  params16(la, Bg, Cg, c, s0, r, w);

  // rT = r^T via 6 squarings (T_ = 64).
  float rT[SG];
#pragma unroll
  for (int i = 0; i < SG; ++i) {
    float t = r[i];
    t *= t; t *= t; t *= t; t *= t; t *= t; t *= t;  // r^64
    rT[i] = t;
  }

  // Carry-in: G = Horner_{j=0..k-1}(rT, E[j])  (coalesced, L2-resident reads)
#pragma unroll
  for (int i = 0; i < SG; ++i) h[i] = 0.0f;
  const float* ebase = E + s0 * CH_ + c;
#pragma unroll 2
  for (int j = 0; j < k; ++j) {
    const float* ep = ebase + (size_t)j * SC;
#pragma unroll
    for (int i = 0; i < SG; ++i) h[i] = fmaf(rT[i], h[i], ep[i * CH_]);
  }

  const float* xp = x + (size_t)k * T_ * CH_ + c;
  float* yp = y + (size_t)k * T_ * CH_;

  for (int l = 0; l < T_; l += 8) {
    float part[8];
#pragma unroll
    for (int jj = 0; jj < 8; ++jj) {
      const float xv = xp[(l + jj) * CH_];
      float a0 = 0, a1 = 0, a2 = 0, a3 = 0;
#pragma unroll
      for (int i = 0; i < SG; i += 4) {
        h[i]     = fmaf(r[i],     h[i],     xv);
        h[i + 1] = fmaf(r[i + 1], h[i + 1], xv);
        h[i + 2] = fmaf(r[i + 2], h[i + 2], xv);
        h[i + 3] = fmaf(r[i + 3], h[i + 3], xv);
        a0 = fmaf(w[i],     h[i],     a0);
        a1 = fmaf(w[i + 1], h[i + 1], a1);
        a2 = fmaf(w[i + 2], h[i + 2], a2);
        a3 = fmaf(w[i + 3], h[i + 3], a3);
      }
      part[jj] = (a0 + a1) + (a2 + a3);
    }

#pragma unroll
    for (int jj = 0; jj < 8; ++jj) lds[g][jj][lane] = part[jj];
    __syncthreads();
#pragma unroll
    for (int p = 0; p < 2; ++p) {
      const int idx = (int)threadIdx.x + p * 256;
      const int jj = idx >> 6;
      const int ln = idx & 63;
      const float vv = (lds[0][jj][ln] + lds[1][jj][ln]) +
                       (lds[2][jj][ln] + lds[3][jj][ln]);
      yp[(size_t)(l + jj) * CH_ + cb + ln] = vv;
    }
    __syncthreads();
  }
}

// ---------------- Degenerate fallback: full-length serial scan --------------
__global__ __launch_bounds__(256) void k_scan_full(const float* __restrict__ x,
                                                   const float* __restrict__ la,
                                                   const float* __restrict__ Bg,
                                                   const float* __restrict__ Cg,
                                                   float* __restrict__ y) {
  __shared__ float lds[4][8][64];
  const int lane = threadIdx.x & 63;
  const int g = threadIdx.x >> 6;
  const int cb = (blockIdx.x & 7) << 6;
  const int c = cb + lane;
  const int s0 = g * SG;

  float r[SG], w[SG], h[SG];
  params16(la, Bg, Cg, c, s0, r, w);
#pragma unroll
  for (int i = 0; i < SG; ++i) h[i] = 0.0f;

  const float* xp = x + c;
  float* yp = y;

  for (int l = 0; l < L_; l += 8) {
    float part[8];
#pragma unroll
    for (int jj = 0; jj < 8; ++jj) {
      const float xv = xp[(size_t)(l + jj) * CH_];
      float a0 = 0, a1 = 0, a2 = 0, a3 = 0;
#pragma unroll
      for (int i = 0; i < SG; i += 4) {
        h[i]     = fmaf(r[i],     h[i],     xv);
        h[i + 1] = fmaf(r[i + 1], h[i + 1], xv);
        h[i + 2] = fmaf(r[i + 2], h[i + 2], xv);
        h[i + 3] = fmaf(r[i + 3], h[i + 3], xv);
        a0 = fmaf(w[i],     h[i],     a0);
        a1 = fmaf(w[i + 1], h[i + 1], a1);
        a2 = fmaf(w[i + 2], h[i + 2], a2);
        a3 = fmaf(w[i + 3], h[i + 3], a3);
      }
      part[jj] = (a0 + a1) + (a2 + a3);
    }
#pragma unroll
    for (int jj = 0; jj < 8; ++jj) lds[g][jj][lane] = part[jj];
    __syncthreads();
#pragma unroll
    for (int p = 0; p < 2; ++p) {
      const int idx = (int)threadIdx.x + p * 256;
      const int jj = idx >> 6;
      const int ln = idx & 63;
      const float vv = (lds[0][jj][ln] + lds[1][jj][ln]) +
                       (lds[2][jj][ln] + lds[3][jj][ln]);
      yp[(size_t)(l + jj) * CH_ + cb + ln] = vv;
    }
    __syncthreads();
  }
}

}  // namespace

extern "C" void kernel_launch(void* const* d_in, const int* in_sizes, int n_in,
                              void* d_out, int out_size, void* d_ws, size_t ws_size,
                              hipStream_t stream) {
  const float* x = (const float*)d_in[0];
  const float* la = (const float*)d_in[1];
  const float* B = (const float*)d_in[2];
  const float* C = (const float*)d_in[3];
  float* y = (float*)d_out;
  float* E = (float*)d_ws;

  const size_t need = (size_t)NC_ * SC * sizeof(float);  // 8 MB
  if (ws_size >= need) {
    k_local<<<NC_ * 8, 256, 0, stream>>>(x, la, E);
    k_scan3<<<NC_ * 8, 256, 0, stream>>>(x, la, B, C, E, y);
  } else {
    k_scan_full<<<8, 256, 0, stream>>>(x, la, B, C, y);
  }
}

// Round 7
// 90.737 us; speedup vs baseline: 1.8937x; 1.8937x over previous
//
#include <hip/hip_runtime.h>

// S4D real: y[l,c] = sum_s w[c,s] * h_s[l],  h_s[l] = x[l,c] + r[c,s]*h_s[l-1]
//
// R12: exact R7 structure (best measured: 92.9us) + latency-exposure fixes.
// Calibrated window model: dur ~= fill(~43us, harness) + kernels(~46us in R7)
// + ~1-2us/boundary. Kernels are 3-4x above BW/VALU floors -> latency-bound.
// R11 lesson: combine must stay O(NC) volume (flat Horner re-read = 104us,
// cache-latency-bound). R9 lesson: no software grid barriers (510us spin).
// Changes vs R7 (mechanical, no structure change):
//   1. Issue-early: cold loads (x batch / E row / k_comb v[]) issued BEFORE
//      the expf param chain so HBM latency overlaps VALU.
//   2. Explicit software pipeline on x: k_local 16-deep, k_scan 8-deep
//      register prefetch, branchless tail (harmless re-load on last iter).
//   3. k_comb: loads-first reorder only.
//   K1 k_local : per-chunk scan (T=64), zero carry-in -> chunk ends E
//   K2 k_comb  : E -> per-chunk carry-INs in place (4 waves x 16 chunks, LDS)
//   K3 k_scan  : seeded re-scan + y = sum_s w*h (LDS cross-wave reduce)

namespace {

constexpr int L_ = 4096;
constexpr int CH_ = 512;
constexpr int S_ = 64;
constexpr float DT = 1.0f / 4096.0f;
constexpr int SC = S_ * CH_;   // 32768 (s,c) pairs
constexpr int SG = 16;         // states per thread (S_ / 4 waves)
constexpr int T_ = 64;         // chunk length
constexpr int NC_ = L_ / T_;   // 64 chunks
constexpr int GJ = 16;         // chunks per combine thread
constexpr int NJ = NC_ / GJ;   // 4 combine groups per (s,c) = waves/block

// Compute r (and optionally w) for states [s0, s0+16) of channel c.
__device__ __forceinline__ void params16(const float* __restrict__ la,
                                         const float* __restrict__ Bg,
                                         const float* __restrict__ Cg,
                                         int c, int s0, float* r, float* w) {
  const float4* lap = reinterpret_cast<const float4*>(la + c * S_ + s0);
  if (w == nullptr) {
#pragma unroll
    for (int q = 0; q < 4; ++q) {
      const float4 v = lap[q];
      const float a[4] = {v.x, v.y, v.z, v.w};
#pragma unroll
      for (int t = 0; t < 4; ++t) {
        const float A = -expf(a[t]);
        r[q * 4 + t] = expf(A * DT);
      }
    }
  } else {
    const float4* bp = reinterpret_cast<const float4*>(Bg + c * S_ + s0);
    const float4* cp = reinterpret_cast<const float4*>(Cg + c * S_ + s0);
#pragma unroll
    for (int q = 0; q < 4; ++q) {
      const float4 v = lap[q], bb = bp[q], cc = cp[q];
      const float a[4] = {v.x, v.y, v.z, v.w};
      const float bv[4] = {bb.x, bb.y, bb.z, bb.w};
      const float cv[4] = {cc.x, cc.y, cc.z, cc.w};
#pragma unroll
      for (int t = 0; t < 4; ++t) {
        const float A = -expf(a[t]);
        const float rr = expf(A * DT);
        r[q * 4 + t] = rr;
        w[q * 4 + t] = cv[t] * ((rr - 1.0f) * bv[t] / A);
      }
    }
  }
}

// ---------------- K1: local chunk-end states (zero carry-in) ----------------
// grid = NC_*8 = 512 blocks, 256 thr. wave g: states [16g,16g+16), lane: c.
__global__ __launch_bounds__(256)
void k_local(const float* __restrict__ x, const float* __restrict__ la,
             float* __restrict__ E) {
  const int lane = threadIdx.x & 63;
  const int g = threadIdx.x >> 6;
  const int k = blockIdx.x >> 3;
  const int c = ((blockIdx.x & 7) << 6) + lane;
  const int s0 = g * SG;

  // Issue the first 16 x loads BEFORE the expf chain (overlap ~900cy HBM).
  const float* xp = x + (size_t)k * T_ * CH_ + c;
  float xb[16];
#pragma unroll
  for (int j = 0; j < 16; ++j) xb[j] = xp[j * CH_];

  float r[SG], h[SG];
  params16(la, nullptr, nullptr, c, s0, r, nullptr);
#pragma unroll
  for (int i = 0; i < SG; ++i) h[i] = 0.0f;

  for (int l0 = 0; l0 < T_; l0 += 16) {
    float xc[16];
#pragma unroll
    for (int j = 0; j < 16; ++j) xc[j] = xb[j];
    const int ln = (l0 + 16 < T_) ? l0 + 16 : l0;  // branchless tail re-load
#pragma unroll
    for (int j = 0; j < 16; ++j) xb[j] = xp[(ln + j) * CH_];
#pragma unroll
    for (int j = 0; j < 16; ++j) {
      const float xv = xc[j];
#pragma unroll
      for (int i = 0; i < SG; ++i) h[i] = fmaf(r[i], h[i], xv);
    }
  }

  float* ew = E + (size_t)k * SC + s0 * CH_ + c;
#pragma unroll
  for (int i = 0; i < SG; ++i) ew[i * CH_] = h[i];
}

// ---------------- K2: chunk ends -> chunk carry-ins (in place) --------------
// Block: 64 pids x NJ waves (wave j owns chunks [GJ*j, GJ*j+GJ)).
__global__ __launch_bounds__(256)
void k_comb(const float* __restrict__ la, float* __restrict__ carry) {
  __shared__ float aggs[NJ][64];
  const int p = threadIdx.x & 63;
  const int j = threadIdx.x >> 6;            // 0..NJ-1, wave-uniform
  const int pid = (blockIdx.x << 6) + p;     // s*CH + c
  const int s = pid >> 9;
  const int c = pid & (CH_ - 1);

  // Loads first: 16 coalesced 256B/wave reads in flight before any VALU.
  float v[GJ];
#pragma unroll
  for (int m = 0; m < GJ; ++m) v[m] = carry[(size_t)(j * GJ + m) * SC + pid];

  const float A = -expf(la[c * S_ + s]);
  const float rT = expf(A * (DT * (float)T_));  // r^T
  float rTG = rT;                                // -> rT^GJ (4 squarings)
  rTG *= rTG;  // ^2
  rTG *= rTG;  // ^4
  rTG *= rTG;  // ^8
  rTG *= rTG;  // ^16

  float agg = 0.0f;
#pragma unroll
  for (int m = 0; m < GJ; ++m) agg = fmaf(rT, agg, v[m]);
  aggs[j][p] = agg;
  __syncthreads();

  float G = 0.0f;  // carry-in of group j
  for (int j2 = 0; j2 < j; ++j2) G = fmaf(rTG, G, aggs[j2][p]);

  float st = G;
#pragma unroll
  for (int m = 0; m < GJ; ++m) {
    carry[(size_t)(j * GJ + m) * SC + pid] = st;  // carry-IN of chunk GJ*j+m
    st = fmaf(rT, st, v[m]);
  }
}

// ---------------- K3: seeded re-scan + output -------------------------------
template <int T, bool USE_CARRY>
__global__ __launch_bounds__(256)
void k_scan(const float* __restrict__ x, const float* __restrict__ la,
            const float* __restrict__ Bg, const float* __restrict__ Cg,
            const float* __restrict__ carry, float* __restrict__ y) {
  __shared__ float lds[4][8][64];  // [s-group][l-row][lane]

  const int lane = threadIdx.x & 63;
  const int g = threadIdx.x >> 6;
  const int k = blockIdx.x >> 3;
  const int cb = (blockIdx.x & 7) << 6;
  const int c = cb + lane;
  const int s0 = g * SG;

  // Issue E row + first 8 x loads BEFORE the param expf/div chain.
  float h[SG];
  if (USE_CARRY) {
    const float* crd = carry + (size_t)k * SC + s0 * CH_ + c;
#pragma unroll
    for (int i = 0; i < SG; ++i) h[i] = crd[i * CH_];
  } else {
#pragma unroll
    for (int i = 0; i < SG; ++i) h[i] = 0.0f;
  }
  const float* xp = x + (size_t)k * T * CH_ + c;
  float xb[8];
#pragma unroll
  for (int j = 0; j < 8; ++j) xb[j] = xp[j * CH_];

  float r[SG], w[SG];
  params16(la, Bg, Cg, c, s0, r, w);

  float* yp = y + (size_t)k * T * CH_;

  for (int l = 0; l < T; l += 8) {
    float xc[8];
#pragma unroll
    for (int j = 0; j < 8; ++j) xc[j] = xb[j];
    const int ln = (l + 8 < T) ? l + 8 : l;  // branchless tail re-load
#pragma unroll
    for (int j = 0; j < 8; ++j) xb[j] = xp[(ln + j) * CH_];

    float part[8];
#pragma unroll
    for (int jj = 0; jj < 8; ++jj) {
      const float xv = xc[jj];
      float a0 = 0, a1 = 0, a2 = 0, a3 = 0;
#pragma unroll
      for (int i = 0; i < SG; i += 4) {
        h[i]     = fmaf(r[i],     h[i],     xv);
        h[i + 1] = fmaf(r[i + 1], h[i + 1], xv);
        h[i + 2] = fmaf(r[i + 2], h[i + 2], xv);
        h[i + 3] = fmaf(r[i + 3], h[i + 3], xv);
        a0 = fmaf(w[i],     h[i],     a0);
        a1 = fmaf(w[i + 1], h[i + 1], a1);
        a2 = fmaf(w[i + 2], h[i + 2], a2);
        a3 = fmaf(w[i + 3], h[i + 3], a3);
      }
      part[jj] = (a0 + a1) + (a2 + a3);
    }

#pragma unroll
    for (int jj = 0; jj < 8; ++jj) lds[g][jj][lane] = part[jj];
    __syncthreads();
#pragma unroll
    for (int p = 0; p < 2; ++p) {
      const int idx = (int)threadIdx.x + p * 256;
      const int jj = idx >> 6;
      const int ln2 = idx & 63;
      const float vv = (lds[0][jj][ln2] + lds[1][jj][ln2]) +
                       (lds[2][jj][ln2] + lds[3][jj][ln2]);
      yp[(size_t)(l + jj) * CH_ + cb + ln2] = vv;
    }
    __syncthreads();
  }
}

}  // namespace

extern "C" void kernel_launch(void* const* d_in, const int* in_sizes, int n_in,
                              void* d_out, int out_size, void* d_ws, size_t ws_size,
                              hipStream_t stream) {
  const float* x = (const float*)d_in[0];
  const float* la = (const float*)d_in[1];
  const float* B = (const float*)d_in[2];
  const float* C = (const float*)d_in[3];
  float* y = (float*)d_out;
  float* E = (float*)d_ws;

  const size_t need = (size_t)NC_ * SC * sizeof(float);  // 8 MB
  if (ws_size >= need) {
    k_local<<<NC_ * 8, 256, 0, stream>>>(x, la, E);
    k_comb<<<SC / 64, 256, 0, stream>>>(la, E);
    k_scan<T_, true><<<NC_ * 8, 256, 0, stream>>>(x, la, B, C, E, y);
  } else {
    k_scan<L_, false><<<8, 256, 0, stream>>>(x, la, B, C, nullptr, y);
  }
}